// Round 9
// baseline (352.762 us; speedup 1.0000x reference)
//
#include <hip/hip_runtime.h>

// B=16, 12 in-ch, 128x128 imgs; conv1->64ch +pool -> 64x64; conv2->128ch (+PE);
// roi max -> out (16,32,128) f32.
//
// R9: single persistent mega-kernel, 512 blocks x 256 thr, 2 blocks/CU
// co-resident (__launch_bounds__(256,2); grid == 2*256 CUs, exclusive GPU).
// Manual device-scope grid barrier (R8's hipLaunchCooperativeKernel never
// executed -- launch rejected; barrier state reset via hipMemsetAsync each
// call for graph-replay determinism). Phases (verbatim R7 kernel bodies):
// P0 prep (imgT, rmask, weight frags) | P1 conv1+pool | P2 conv2+PE ->bf16
// | P3 roi-max packed-u16 partials | P4 merge+unmap.

typedef __attribute__((ext_vector_type(8))) short short8;   // MFMA bf16 A/B frag
typedef __attribute__((ext_vector_type(4))) float f32x4;    // MFMA C/D frag
typedef __attribute__((ext_vector_type(4))) unsigned short us4;
typedef __attribute__((ext_vector_type(2))) unsigned short u16x2;
typedef unsigned short u16;
typedef unsigned int u32;

__device__ __forceinline__ u16 f2bf(float f) {  // RNE f32 -> bf16 bits
  u32 u = __builtin_bit_cast(u32, f);
  return (u16)((u + 0x7fffu + ((u >> 16) & 1u)) >> 16);
}
__device__ __forceinline__ u32 pkmaxu(u32 a, u32 b) {  // v_pk_max_u16
  u16x2 x = __builtin_bit_cast(u16x2, a), y = __builtin_bit_cast(u16x2, b);
  return __builtin_bit_cast(u32, __builtin_elementwise_max(x, y));
}
__device__ __forceinline__ u32 map2(u32 v) {  // monotone bf16->u16 map, x2
  u32 flip = ((v & 0x80008000u) >> 15) * 0xFFFFu;
  return v ^ (flip | 0x80008000u);
}
__device__ __forceinline__ float unmap1(u32 m) {  // mapped u16 -> f32
  u32 b = m ^ ((m & 0x8000u) ? 0x8000u : 0xFFFFu);
  return __builtin_bit_cast(float, b << 16);
}

namespace {

// Device-scope sense-counting grid barrier. bar[0]=arrivals, bar[1]=gen.
// Release fence (flush XCD L2) before arrival; acquire fence after exit.
// Gen-relative spin: works for any initial gen; counter must start 0
// (kernel_launch memsets bar each call). Spin bounded: co-residency
// failure -> wrong output, never a hang.
__device__ __forceinline__ void gbar(u32* bar, u32 nb) {
  __syncthreads();
  if (threadIdx.x == 0) {
    __threadfence();  // release: this block's writes -> device scope
    const u32 my = __hip_atomic_load(&bar[1], __ATOMIC_RELAXED,
                                     __HIP_MEMORY_SCOPE_AGENT);
    const u32 old = __hip_atomic_fetch_add(&bar[0], 1u, __ATOMIC_ACQ_REL,
                                           __HIP_MEMORY_SCOPE_AGENT);
    if (old == nb - 1u) {
      __hip_atomic_store(&bar[0], 0u, __ATOMIC_RELAXED,
                         __HIP_MEMORY_SCOPE_AGENT);
      __hip_atomic_fetch_add(&bar[1], 1u, __ATOMIC_RELEASE,
                             __HIP_MEMORY_SCOPE_AGENT);  // orders cnt reset first
    } else {
      int guard = 0;
      while (__hip_atomic_load(&bar[1], __ATOMIC_RELAXED,
                               __HIP_MEMORY_SCOPE_AGENT) == my) {
        if (++guard > (1 << 24)) break;  // safety valve
        __builtin_amdgcn_s_sleep(8);
      }
    }
    __threadfence();  // acquire: invalidate stale L1/L2
  }
  __syncthreads();
}

__global__ __launch_bounds__(256, 2) void mega(
    const float* __restrict__ img, u16* __restrict__ imgT,
    const unsigned* __restrict__ rois, unsigned* __restrict__ rmask,
    const float* __restrict__ w1, const float* __restrict__ w2,
    u16* __restrict__ Aw1, u16* __restrict__ Aw2,
    const float* __restrict__ b1, u16* __restrict__ pooledT,
    const float* __restrict__ b2, const float* __restrict__ dw,
    const float* __restrict__ db, u16* __restrict__ x2b,
    u32* __restrict__ partial, float* __restrict__ out,
    u32* __restrict__ bar) {
  __shared__ alignas(16) char LB[25088];  // max phase: P1 (16384 SIMG + 8704 PT)
  const int g = blockIdx.x;  // 0..511
  const int t = threadIdx.x;

  // ================= P0: imgT (2048 u) | rmask (128 u) | wprep (328 u) ======
  for (int u = g; u < 2504; u += 512) {
    if (u < 2048) {  // images f32 -> bf16 imgT [b][row][col][ci16], pad ci->0
      u16* ST = (u16*)LB;  // [col 0..127][cip 0..15]
      __syncthreads();     // WAR guard: LDS reuse across units
      const int row = u & 127, b = u >> 7;
#pragma unroll
      for (int i = 0; i < 2; ++i) {
        const int e = i * 256 + t;
        ST[(e >> 2) * 16 + 12 + (e & 3)] = 0;
      }
#pragma unroll
      for (int i = 0; i < 6; ++i) {
        const int e = i * 256 + t;
        const int ci = e >> 7, col = e & 127;
        const float v = img[(((size_t)(b * 12 + ci)) << 14) + row * 128 + col];
        ST[col * 16 + ci] = f2bf(v);
      }
      __syncthreads();
      us4* dst = (us4*)(imgT + (((size_t)(b * 128 + row)) << 11));
#pragma unroll
      for (int i = 0; i < 2; ++i) {
        const int q = i * 256 + t;
        dst[q] = *(const us4*)&ST[q * 4];
      }
    } else if (u < 2176) {  // rois[:,:,::2,::2] -> 32-bit object mask
      const int lane = t & 63;
      u32 ok = 1u;
#pragma unroll
      for (int i = 0; i < 4; ++i) {
        u32 v = rois[lane * 4 + i];
        ok &= ((v <= 1u) || (v == 0x3f800000u)) ? 1u : 0u;
      }
      const bool isWord = (__all((int)ok) != 0);
      const unsigned char* roisB = (const unsigned char*)rois;
      const int pi = (u - 2048) * 256 + t;  // 0..32767
      const int b = pi >> 11;
      const int pp = pi & 2047;
      const int h = pp >> 5;
      const int wp = pp & 31;
      const size_t base = (size_t)b * 32 * 16384 + (size_t)(2 * h) * 128 + 4 * wp;
      u32 m0 = 0, m1 = 0;
#pragma unroll
      for (int o = 0; o < 32; ++o) {
        const size_t idx = base + (size_t)o * 16384;
        if (isWord) {
          const uint4 q = *(const uint4*)&rois[idx];
          m0 |= (u32)(q.x != 0u) << o;
          m1 |= (u32)(q.z != 0u) << o;
        } else {
          const u32 q = *(const u32*)&roisB[idx];
          m0 |= (u32)((q & 0xffu) != 0u) << o;
          m1 |= (u32)((q & 0xff0000u) != 0u) << o;
        }
      }
      *(uint2*)&rmask[b * 4096 + h * 64 + wp * 2] = make_uint2(m0, m1);
    } else if (u < 2464) {  // w2 -> Aw2 frags: k=32ks+g8+j -> (rc=k>>6, ci=k&63)
      const int idx = (u - 2176) * 256 + t;  // 0..73727
      const int j = idx & 7;
      const int lane = (idx >> 3) & 63;
      const int t3 = idx >> 9;
      const int ks = t3 % 18, cot = t3 / 18;
      const int m = lane & 15, gg = lane >> 4;
      const int co = cot * 16 + m;
      const int k = ks * 32 + gg * 8 + j;
      const int rc = k >> 6, ci = k & 63;
      Aw2[idx] = f2bf(w2[co * 576 + ci * 9 + rc]);
    } else {  // w1 -> Aw1 frags, K padded 108->160
      const int idx = (u - 2464) * 256 + t;  // 0..10239
      const int j = idx & 7;
      const int lane = (idx >> 3) & 63;
      const int t3 = idx >> 9;
      const int ks = t3 % 5, cot = t3 / 5;
      const int m = lane & 15, gg = lane >> 4;
      const int co = cot * 16 + m;
      const int k = ks * 32 + gg * 8 + j;
      const int rc = k >> 4, cip = k & 15;
      const float v = (rc < 9 && cip < 12) ? w1[co * 108 + cip * 9 + rc] : 0.f;
      Aw1[idx] = f2bf(v);
    }
  }
  gbar(bar, 512);

  // ================= P1: conv1 (MFMA) + bias + relu + pool -> pooledT =======
  for (int u = g; u < 1024; u += 512) {
    u16* SIMG = (u16*)LB;          // 16 KB, swizzled
    u16* PT = (u16*)(LB + 16384);  // [pw][co], stride 68
    __syncthreads();               // WAR guard
    const int h2 = u & 63, b = u >> 6;
    const int wv = t >> 6, l = t & 63;

#pragma unroll
    for (int i = 0; i < 4; ++i) {  // stage 4 rows x 4KB (swizzled store)
      const int q = i * 256 + t;
      const int sr = q >> 8, off = q & 255;
      const int irow = 2 * h2 - 1 + sr;
      short8 v = {0, 0, 0, 0, 0, 0, 0, 0};
      if ((unsigned)irow < 128u)
        v = *(const short8*)(imgT + (((size_t)(b * 128 + irow)) << 11) + off * 8);
      *(short8*)((char*)SIMG + ((q * 16) ^ (((q >> 3) & 1) << 4))) = v;
    }
    __syncthreads();

    const int m16 = l & 15, gg = l >> 4;
    const int colhalf = wv >> 1, cotbase = (wv & 1) * 2;
    const int cipb = (gg & 1) * 16;
    f32x4 acc[2][8];
#pragma unroll
    for (int ct = 0; ct < 2; ++ct)
#pragma unroll
      for (int pt = 0; pt < 8; ++pt) acc[ct][pt] = (f32x4){0.f, 0.f, 0.f, 0.f};

    const u16* awb = Aw1 + (size_t)l * 8;
    const short8 z8 = {0, 0, 0, 0, 0, 0, 0, 0};

#pragma unroll
    for (int ks = 0; ks < 5; ++ks) {
      short8 a0 = *(const short8*)(awb + (cotbase * 5 + ks) * 512);
      short8 a1 = *(const short8*)(awb + ((cotbase + 1) * 5 + ks) * 512);
      const bool pz = (ks == 4) && (gg >= 2);  // zero-padded K slots
      const int rc = pz ? 0 : (2 * ks + (gg >> 1));
      const int rr = (rc * 11) >> 5;  // rc/3
      const int cc = rc - rr * 3;     // rc%3
      const int d = m16 - 1 + cc;     // -1..16
      const int sb = (d < 0) ? 1 : ((d >> 2) & 1);
      const int base = rr * 4096 + d * 32 + colhalf * 2048 + (cipb ^ (sb << 4));
      const bool killLo = (cc == 0) && (m16 == 0) && (colhalf == 0);
      const bool killHi = (cc == 2) && (m16 == 15) && (colhalf == 1);
#pragma unroll
      for (int pt = 0; pt < 8; ++pt) {
        const int r01 = pt >> 2, ct2 = pt & 3;
        short8 bv = *(const short8*)((const char*)SIMG + base + r01 * 4096 + ct2 * 512);
        bool kill = pz;
        if (ct2 == 0) kill = kill || killLo;
        if (ct2 == 3) kill = kill || killHi;
        if (kill) bv = z8;
        acc[0][pt] = __builtin_amdgcn_mfma_f32_16x16x32_bf16(a0, bv, acc[0][pt], 0, 0, 0);
        acc[1][pt] = __builtin_amdgcn_mfma_f32_16x16x32_bf16(a1, bv, acc[1][pt], 0, 0, 0);
      }
    }

    // relu + 2x2 pool -> PT[pw][co]
#pragma unroll
    for (int ct = 0; ct < 2; ++ct) {
      const int cot = cotbase + ct;
#pragma unroll
      for (int r = 0; r < 4; ++r) {
        const int co = cot * 16 + gg * 4 + r;
        const float bias = b1[co];
#pragma unroll
        for (int ct2 = 0; ct2 < 4; ++ct2) {
          float v0 = fmaxf(acc[ct][ct2][r] + bias, 0.f);
          float v1 = fmaxf(acc[ct][4 + ct2][r] + bias, 0.f);
          float vv = fmaxf(v0, v1);
          vv = fmaxf(vv, __shfl_xor(vv, 1, 64));
          if (!(m16 & 1)) {
            const int pw = colhalf * 32 + ct2 * 8 + (m16 >> 1);
            PT[pw * 68 + co] = f2bf(vv);
          }
        }
      }
    }
    __syncthreads();
    u16* dst = pooledT + (((size_t)(b * 64 + h2)) << 12);
#pragma unroll
    for (int i = 0; i < 4; ++i) {
      const int e = (i * 256 + t) * 4;
      const int pw = e >> 6, co = e & 63;
      *(us4*)(dst + e) = *(const us4*)&PT[pw * 68 + co];
    }
  }
  gbar(bar, 512);

  // ================= P2: conv2 (MFMA) + bias + relu + PE -> x2b bf16 ========
  for (int u = g; u < 1024; u += 512) {
    char* SB = LB;  // 24 KB staged rows, T2 XOR swizzle
    __syncthreads();
    const int h = u & 63, b = u >> 6;
    const int wv = t >> 6, l = t & 63;

#pragma unroll
    for (int i = 0; i < 6; ++i) {
      const int chunk = i * 4 + wv;
      const int row = chunk >> 3;
      const int hin = h - 1 + row;
      short8 v = {0, 0, 0, 0, 0, 0, 0, 0};
      if ((unsigned)hin < 64u)
        v = *(const short8*)(pooledT + (((size_t)(b * 64 + hin)) << 12) +
                             ((chunk & 7) << 9) + l * 8);
      const int lin = chunk * 1024 + l * 16;
      *(short8*)(SB + (lin ^ (((lin >> 7) & 7) << 4))) = v;
    }
    __syncthreads();

    const int m16 = l & 15, gg = l >> 4;
    const int kbyte = gg * 16;
    f32x4 acc[2][4];
#pragma unroll
    for (int ct = 0; ct < 2; ++ct)
#pragma unroll
      for (int n = 0; n < 4; ++n) acc[ct][n] = (f32x4){0.f, 0.f, 0.f, 0.f};

    const u16* aw0 = Aw2 + (size_t)wv * 36 * 512 + l * 8;  // cot = 2wv
    const short8 z8 = {0, 0, 0, 0, 0, 0, 0, 0};

#pragma unroll
    for (int ks = 0; ks < 18; ++ks) {
      const int rc = ks >> 1, r = rc / 3, c = rc % 3;  // compile-time
      const int koff = r * 8192 + (ks & 1) * 64 + kbyte;
      short8 a0 = *(const short8*)(aw0 + ks * 512);
      short8 a1 = *(const short8*)(aw0 + (18 + ks) * 512);
      const int d = m16 + c - 1;  // -1..16
      const int base = (koff + d * 128) ^ ((d & 7) << 4);
      const bool edgeLo = (c == 0) && (m16 == 0);
      const bool edgeHi = (c == 2) && (m16 == 15);
#pragma unroll
      for (int n = 0; n < 4; ++n) {
        short8 bv = *(const short8*)(SB + base + n * 2048);
        if (c == 0 && n == 0) { if (edgeLo) bv = z8; }
        if (c == 2 && n == 3) { if (edgeHi) bv = z8; }
        acc[0][n] = __builtin_amdgcn_mfma_f32_16x16x32_bf16(a0, bv, acc[0][n], 0, 0, 0);
        acc[1][n] = __builtin_amdgcn_mfma_f32_16x16x32_bf16(a1, bv, acc[1][n], 0, 0, 0);
      }
    }

    const float inv63 = 1.f / 63.f;
    const float gy = (float)h * inv63;
#pragma unroll
    for (int ct = 0; ct < 2; ++ct) {
      const int cot = wv * 2 + ct;
#pragma unroll
      for (int r = 0; r < 4; ++r) {
        const int co = cot * 16 + gg * 4 + r;
        const float bias = b2[co];
        const float W0 = dw[co * 4 + 0], W1 = dw[co * 4 + 1];
        const float W2 = dw[co * 4 + 2], W3 = dw[co * 4 + 3];
        const float pe0 = gy * (W0 - W2) + W2 + W3 + db[co];
        const float s13 = W1 - W3;
        u16* orow = x2b + (((size_t)(b * 128 + co)) << 12) + h * 64;
#pragma unroll
        for (int n = 0; n < 4; ++n) {
          const int w = n * 16 + m16;
          orow[w] = f2bf(fmaxf(acc[ct][n][r] + bias, 0.f) + pe0 + (float)w * inv63 * s13);
        }
      }
    }
  }
  gbar(bar, 512);

  // ================= P3: roi-max, packed mapped-u16 -> partial ==============
  for (int u = g; u < 1024; u += 512) {
    u32* XSU = (u32*)LB;           // [16 c][260] (256 used)
    u32* MS = (u32*)(LB + 16640);  // 512 mask words
    __syncthreads();               // WAR guard
    const int cgi = u & 7, pq = (u >> 3) & 7, b = u >> 6;
    const int wv = t >> 6, lane = t & 63;
    const int p0 = pq * 512;

#pragma unroll
    for (int i = 0; i < 4; ++i) {  // stage+map 16 c x 512 pos
      const int f4 = i * 256 + t;
      const int c = f4 >> 6, cidx = f4 & 63;
      uint4 v = *(const uint4*)&x2b[(((size_t)(b * 128 + cgi * 16 + c)) << 12) + p0 + cidx * 8];
      v.x = map2(v.x); v.y = map2(v.y); v.z = map2(v.z); v.w = map2(v.w);
      *(uint4*)&XSU[c * 260 + cidx * 4] = v;
    }
    if (t < 128) *(uint4*)&MS[t * 4] = *(const uint4*)&rmask[b * 4096 + p0 + t * 4];
    __syncthreads();

    const int og = lane >> 3, cu = lane & 7;
    const u32* r0 = XSU + (2 * cu) * 260;
    const u32* r1 = XSU + (2 * cu + 1) * 260;
    const int ps = wv * 128;

    u32 a[4][2];  // packed running max; 0 = mapped -inf
#pragma unroll
    for (int r = 0; r < 4; ++r) { a[r][0] = 0u; a[r][1] = 0u; }

    for (int pi = 0; pi < 32; ++pi) {
      const int p = ps + pi * 4;
      const uint4 mw = *(const uint4*)&MS[p];  // uniform -> broadcast
      const uint2 xa = *(const uint2*)&r0[p >> 1];
      const uint2 xb = *(const uint2*)&r1[p >> 1];
#pragma unroll
      for (int r = 0; r < 4; ++r) {
        const int o = og * 4 + r;
        u32 t0 = (u32)((int)(mw.x << (31 - o)) >> 31);
        u32 t1 = (u32)((int)(mw.y << (31 - o)) >> 31);
        u32 pm = (t0 & 0xFFFFu) | (t1 & 0xFFFF0000u);
        a[r][0] = pkmaxu(a[r][0], (xa.x & pm) | (0x80008000u & ~pm));
        a[r][1] = pkmaxu(a[r][1], (xb.x & pm) | (0x80008000u & ~pm));
        t0 = (u32)((int)(mw.z << (31 - o)) >> 31);
        t1 = (u32)((int)(mw.w << (31 - o)) >> 31);
        pm = (t0 & 0xFFFFu) | (t1 & 0xFFFF0000u);
        a[r][0] = pkmaxu(a[r][0], (xa.y & pm) | (0x80008000u & ~pm));
        a[r][1] = pkmaxu(a[r][1], (xb.y & pm) | (0x80008000u & ~pm));
      }
    }

    __syncthreads();     // XSU/MS dead; reuse LB for reduction
    u32* RED = (u32*)LB; // [4 wv][64 lane][8 slot]
#pragma unroll
    for (int r = 0; r < 4; ++r) {  // static indices only (rule #20)
      RED[(wv * 64 + lane) * 8 + r * 2 + 0] = a[r][0];
      RED[(wv * 64 + lane) * 8 + r * 2 + 1] = a[r][1];
    }
    __syncthreads();
    {
      const int o = t >> 3, clp = t & 7;
      const int sl = (o >> 2) * 8 + clp;
      const int s0 = (o & 3) * 2;
      u32 m0 = 0u, m1 = 0u;
#pragma unroll
      for (int w = 0; w < 4; ++w) {
        const uint2 q = *(const uint2*)&RED[(w * 64 + sl) * 8 + s0];
        m0 = pkmaxu(m0, q.x);
        m1 = pkmaxu(m1, q.y);
      }
      u32 f0l = m0 & 0xFFFFu, f0h = m0 >> 16;
      u32 f1l = m1 & 0xFFFFu, f1h = m1 >> 16;
      const u32 f0 = f0l > f0h ? f0l : f0h;
      const u32 f1 = f1l > f1h ? f1l : f1h;
      partial[(size_t)pq * 32768 + ((size_t)b * 32 + o) * 64 + cgi * 8 + clp] =
          f0 | (f1 << 16);
    }
  }
  gbar(bar, 512);

  // ================= P4: merge 8 pq-partials, unmap -> f32 out ==============
  if (g < 128) {
    const int idx = g * 256 + t;  // 0..32767 u32s
    u32 v = partial[idx];
#pragma unroll
    for (int q = 1; q < 8; ++q) v = pkmaxu(v, partial[q * 32768 + idx]);
    float2 o2;
    o2.x = unmap1(v & 0xFFFFu);
    o2.y = unmap1(v >> 16);
    *(float2*)&out[idx * 2] = o2;
  }
}

}  // namespace

extern "C" void kernel_launch(void* const* d_in, const int* in_sizes, int n_in,
                              void* d_out, int out_size, void* d_ws, size_t ws_size,
                              hipStream_t stream) {
  const float* images = (const float*)d_in[0];
  const unsigned* rois = (const unsigned*)d_in[1];
  const float* w1 = (const float*)d_in[2];
  const float* b1 = (const float*)d_in[3];
  const float* w2 = (const float*)d_in[4];
  const float* b2 = (const float*)d_in[5];
  const float* dw = (const float*)d_in[6];
  const float* db = (const float*)d_in[7];
  float* out = (float*)d_out;

  char* ws = (char*)d_ws;
  // rmask 256KB @0 ; pooledT 8MB @0x40000 (dead after P2; partial 1MB reuses);
  // Aw2 144KB @0x840000 ; Aw1 20KB @0x864000 ; bar 8B @0x870000 ;
  // imgT 8MB @0x900000 (dead after P1) ; x2b bf16 16MB @0x900000 (overlaps).
  unsigned* rmask = (unsigned*)(ws);
  u16* pooledT = (u16*)(ws + 0x40000);
  u16* Aw2 = (u16*)(ws + 0x840000);
  u16* Aw1 = (u16*)(ws + 0x864000);
  u32* bar = (u32*)(ws + 0x870000);
  u16* imgT = (u16*)(ws + 0x900000);
  u16* x2b = (u16*)(ws + 0x900000);
  u32* partial = (u32*)(ws + 0x40000);

  // Barrier state MUST start at {0,0} every call (d_ws poisoned 0xAA once,
  // never re-poisoned; gen is start-relative but the counter must be 0).
  hipMemsetAsync(bar, 0, 8, stream);
  hipLaunchKernelGGL(mega, dim3(512), dim3(256), 0, stream,
                     images, imgT, rois, rmask, w1, w2, Aw1, Aw2, b1, pooledT,
                     b2, dw, db, x2b, partial, out, bar);
}

// Round 10
// 71.624 us; speedup vs baseline: 4.9252x; 4.9252x over previous
//
#include <hip/hip_runtime.h>

// B=16, 12 in-ch, 128x128 imgs; conv1->64ch +pool -> 64x64; conv2->128ch (+PE);
// roi max -> out (16,32,128) f32.
//
// R10 = R7 (best, 72.6us) + fused prep + 2-row k2 blocks. R9 lesson: software
// grid barriers cost ~330us (fence-driven L2 flush storms); separate graph'd
// launches are cheap. Pipeline: kiop (imgT+rmask+weight frags) ; k1_mfma
// (conv1+relu+pool -> bf16 pooledT) ; k2_mfma (conv2+relu+PE -> bf16 x2b,
// 2 rows/block) ; k3_roi (masked max, packed mapped-u16) ; k4_merge.

typedef __attribute__((ext_vector_type(8))) short short8;   // MFMA bf16 A/B frag
typedef __attribute__((ext_vector_type(4))) float f32x4;    // MFMA C/D frag
typedef __attribute__((ext_vector_type(4))) unsigned short us4;
typedef __attribute__((ext_vector_type(2))) unsigned short u16x2;
typedef unsigned short u16;
typedef unsigned int u32;

__device__ __forceinline__ u16 f2bf(float f) {  // RNE f32 -> bf16 bits
  u32 u = __builtin_bit_cast(u32, f);
  return (u16)((u + 0x7fffu + ((u >> 16) & 1u)) >> 16);
}
__device__ __forceinline__ u32 pkmaxu(u32 a, u32 b) {  // v_pk_max_u16
  u16x2 x = __builtin_bit_cast(u16x2, a), y = __builtin_bit_cast(u16x2, b);
  return __builtin_bit_cast(u32, __builtin_elementwise_max(x, y));
}
__device__ __forceinline__ u32 map2(u32 v) {  // monotone bf16->u16 map, x2
  u32 flip = ((v & 0x80008000u) >> 15) * 0xFFFFu;
  return v ^ (flip | 0x80008000u);
}
__device__ __forceinline__ float unmap1(u32 m) {  // mapped u16 -> f32
  u32 b = m ^ ((m & 0x8000u) ? 0x8000u : 0xFFFFu);
  return __builtin_bit_cast(float, b << 16);
}

namespace {

// ---------------- kiop: imgT | rmask | Aw2 | Aw1 (fused prep) ----------------
__global__ __launch_bounds__(256) void kiop(const float* __restrict__ img,
                                            u16* __restrict__ imgT,
                                            const unsigned* __restrict__ rois,
                                            unsigned* __restrict__ rmask,
                                            const float* __restrict__ w2,
                                            u16* __restrict__ Aw2,
                                            const float* __restrict__ w1,
                                            u16* __restrict__ Aw1) {
  __shared__ alignas(16) u16 ST[2048];
  const int bx = blockIdx.x;
  const int t = threadIdx.x;
  if (bx < 2048) {  // images f32 -> bf16 imgT [b][row][col][ci16], pad ci->0
    const int row = bx & 127, b = bx >> 7;
#pragma unroll
    for (int i = 0; i < 2; ++i) {
      const int e = i * 256 + t;
      ST[(e >> 2) * 16 + 12 + (e & 3)] = 0;
    }
#pragma unroll
    for (int i = 0; i < 6; ++i) {
      const int e = i * 256 + t;
      const int ci = e >> 7, col = e & 127;
      const float v = img[(((size_t)(b * 12 + ci)) << 14) + row * 128 + col];
      ST[col * 16 + ci] = f2bf(v);
    }
    __syncthreads();
    us4* dst = (us4*)(imgT + (((size_t)(b * 128 + row)) << 11));
#pragma unroll
    for (int i = 0; i < 2; ++i) {
      const int q = i * 256 + t;
      dst[q] = *(const us4*)&ST[q * 4];
    }
  } else if (bx < 2176) {  // rois[:,:,::2,::2] -> 32-bit object mask
    const int lane = t & 63;
    u32 ok = 1u;
#pragma unroll
    for (int i = 0; i < 4; ++i) {
      u32 v = rois[lane * 4 + i];
      ok &= ((v <= 1u) || (v == 0x3f800000u)) ? 1u : 0u;
    }
    const bool isWord = (__all((int)ok) != 0);
    const unsigned char* roisB = (const unsigned char*)rois;
    const int pi = (bx - 2048) * 256 + t;  // 0..32767
    const int b = pi >> 11;
    const int pp = pi & 2047;
    const int h = pp >> 5;
    const int wp = pp & 31;
    const size_t base = (size_t)b * 32 * 16384 + (size_t)(2 * h) * 128 + 4 * wp;
    u32 m0 = 0, m1 = 0;
#pragma unroll
    for (int o = 0; o < 32; ++o) {
      const size_t idx = base + (size_t)o * 16384;
      if (isWord) {
        const uint4 q = *(const uint4*)&rois[idx];
        m0 |= (u32)(q.x != 0u) << o;
        m1 |= (u32)(q.z != 0u) << o;
      } else {
        const u32 q = *(const u32*)&roisB[idx];
        m0 |= (u32)((q & 0xffu) != 0u) << o;
        m1 |= (u32)((q & 0xff0000u) != 0u) << o;
      }
    }
    *(uint2*)&rmask[b * 4096 + h * 64 + wp * 2] = make_uint2(m0, m1);
  } else if (bx < 2464) {  // w2 -> Aw2 frags
    const int idx = (bx - 2176) * 256 + t;  // 0..73727
    const int j = idx & 7;
    const int lane = (idx >> 3) & 63;
    const int t3 = idx >> 9;
    const int ks = t3 % 18, cot = t3 / 18;
    const int m = lane & 15, g = lane >> 4;
    const int co = cot * 16 + m;
    const int k = ks * 32 + g * 8 + j;
    const int rc = k >> 6, ci = k & 63;
    Aw2[idx] = f2bf(w2[co * 576 + ci * 9 + rc]);
  } else {  // w1 -> Aw1 frags, K padded 108->160
    const int idx = (bx - 2464) * 256 + t;  // 0..10239
    const int j = idx & 7;
    const int lane = (idx >> 3) & 63;
    const int t3 = idx >> 9;
    const int ks = t3 % 5, cot = t3 / 5;
    const int m = lane & 15, g = lane >> 4;
    const int co = cot * 16 + m;
    const int k = ks * 32 + g * 8 + j;
    const int rc = k >> 4, cip = k & 15;
    const float v = (rc < 9 && cip < 12) ? w1[co * 108 + cip * 9 + rc] : 0.f;
    Aw1[idx] = f2bf(v);
  }
}

// ---------------- k1: conv1 (MFMA) + bias + relu + pool -> pooledT bf16 ------
__global__ __launch_bounds__(256) void k1_mfma(const u16* __restrict__ imgT,
                                               const u16* __restrict__ Aw1,
                                               const float* __restrict__ b1,
                                               u16* __restrict__ pooledT) {
  __shared__ alignas(16) u16 SIMG[8192];   // 16 KB, swizzled
  __shared__ alignas(16) u16 PT[64 * 68];  // pooled [pw][co]
  const int h2 = blockIdx.x, b = blockIdx.y;
  const int t = threadIdx.x, wv = t >> 6, l = t & 63;

#pragma unroll
  for (int i = 0; i < 4; ++i) {  // stage 4 rows x 4KB (swizzled store)
    const int q = i * 256 + t;
    const int sr = q >> 8, off = q & 255;
    const int irow = 2 * h2 - 1 + sr;
    short8 v = {0, 0, 0, 0, 0, 0, 0, 0};
    if ((unsigned)irow < 128u)
      v = *(const short8*)(imgT + (((size_t)(b * 128 + irow)) << 11) + off * 8);
    *(short8*)((char*)SIMG + ((q * 16) ^ (((q >> 3) & 1) << 4))) = v;
  }
  __syncthreads();

  const int m16 = l & 15, g = l >> 4;
  const int colhalf = wv >> 1, cotbase = (wv & 1) * 2;
  const int cipb = (g & 1) * 16;
  f32x4 acc[2][8];
#pragma unroll
  for (int ct = 0; ct < 2; ++ct)
#pragma unroll
    for (int pt = 0; pt < 8; ++pt) acc[ct][pt] = (f32x4){0.f, 0.f, 0.f, 0.f};

  const u16* awb = Aw1 + (size_t)l * 8;
  const short8 z8 = {0, 0, 0, 0, 0, 0, 0, 0};

#pragma unroll
  for (int ks = 0; ks < 5; ++ks) {
    short8 a0 = *(const short8*)(awb + (cotbase * 5 + ks) * 512);
    short8 a1 = *(const short8*)(awb + ((cotbase + 1) * 5 + ks) * 512);
    const bool pz = (ks == 4) && (g >= 2);  // zero-padded K slots
    const int rc = pz ? 0 : (2 * ks + (g >> 1));
    const int rr = (rc * 11) >> 5;  // rc/3
    const int cc = rc - rr * 3;     // rc%3
    const int d = m16 - 1 + cc;     // -1..16
    const int sb = (d < 0) ? 1 : ((d >> 2) & 1);
    const int base = rr * 4096 + d * 32 + colhalf * 2048 + (cipb ^ (sb << 4));
    const bool killLo = (cc == 0) && (m16 == 0) && (colhalf == 0);
    const bool killHi = (cc == 2) && (m16 == 15) && (colhalf == 1);
#pragma unroll
    for (int pt = 0; pt < 8; ++pt) {
      const int r01 = pt >> 2, ct2 = pt & 3;
      short8 bv = *(const short8*)((const char*)SIMG + base + r01 * 4096 + ct2 * 512);
      bool kill = pz;
      if (ct2 == 0) kill = kill || killLo;
      if (ct2 == 3) kill = kill || killHi;
      if (kill) bv = z8;
      acc[0][pt] = __builtin_amdgcn_mfma_f32_16x16x32_bf16(a0, bv, acc[0][pt], 0, 0, 0);
      acc[1][pt] = __builtin_amdgcn_mfma_f32_16x16x32_bf16(a1, bv, acc[1][pt], 0, 0, 0);
    }
  }

  // relu + 2x2 pool -> PT[pw][co]
#pragma unroll
  for (int ct = 0; ct < 2; ++ct) {
    const int cot = cotbase + ct;
#pragma unroll
    for (int r = 0; r < 4; ++r) {
      const int co = cot * 16 + g * 4 + r;
      const float bias = b1[co];
#pragma unroll
      for (int ct2 = 0; ct2 < 4; ++ct2) {
        float v0 = fmaxf(acc[ct][ct2][r] + bias, 0.f);
        float v1 = fmaxf(acc[ct][4 + ct2][r] + bias, 0.f);
        float vv = fmaxf(v0, v1);
        vv = fmaxf(vv, __shfl_xor(vv, 1, 64));
        if (!(m16 & 1)) {
          const int pw = colhalf * 32 + ct2 * 8 + (m16 >> 1);
          PT[pw * 68 + co] = f2bf(vv);
        }
      }
    }
  }
  __syncthreads();
  u16* dst = pooledT + (((size_t)(b * 64 + h2)) << 12);
#pragma unroll
  for (int i = 0; i < 4; ++i) {
    const int e = (i * 256 + t) * 4;
    const int pw = e >> 6, co = e & 63;
    *(us4*)(dst + e) = *(const us4*)&PT[pw * 68 + co];
  }
}

// ---------------- k2: conv2 (MFMA) + bias + relu + PE -> x2b bf16 ------------
// v2: 2 output rows per block (grid 32x16). Stage rows 2hp-1..2hp+2 as
// [4][64col][64ci] (32KB, T2 XOR swizzle). A-frag loads amortized over both
// rows (halves Aw2 traffic); staging redundancy 3x -> 2x; 72 MFMA/wave/stage.
__global__ __launch_bounds__(256) void k2_mfma(const u16* __restrict__ pooledT,
                                               const u16* __restrict__ Aw,
                                               const float* __restrict__ b2,
                                               const float* __restrict__ dw,
                                               const float* __restrict__ db,
                                               u16* __restrict__ x2b) {
  __shared__ alignas(16) char SB[32768];  // 4 rows x 8KB
  const int hp = blockIdx.x, b = blockIdx.y;
  const int t = threadIdx.x, wv = t >> 6, l = t & 63;

#pragma unroll
  for (int i = 0; i < 8; ++i) {  // 32 chunks x 1KB
    const int chunk = i * 4 + wv;
    const int row = chunk >> 3;
    const int hin = 2 * hp - 1 + row;
    short8 v = {0, 0, 0, 0, 0, 0, 0, 0};
    if ((unsigned)hin < 64u)
      v = *(const short8*)(pooledT + (((size_t)(b * 64 + hin)) << 12) +
                           ((chunk & 7) << 9) + l * 8);
    const int lin = chunk * 1024 + l * 16;
    *(short8*)(SB + (lin ^ (((lin >> 7) & 7) << 4))) = v;
  }
  __syncthreads();

  const int m16 = l & 15, g = l >> 4;
  const int kbyte = g * 16;
  f32x4 acc[2][8];  // [ct][n], n = or*4 + n4
#pragma unroll
  for (int ct = 0; ct < 2; ++ct)
#pragma unroll
    for (int n = 0; n < 8; ++n) acc[ct][n] = (f32x4){0.f, 0.f, 0.f, 0.f};

  const u16* aw0 = Aw + (size_t)wv * 36 * 512 + l * 8;  // cot = 2wv
  const short8 z8 = {0, 0, 0, 0, 0, 0, 0, 0};

#pragma unroll
  for (int ks = 0; ks < 18; ++ks) {
    const int rc = ks >> 1, r = rc / 3, c = rc % 3;  // compile-time
    const int koff = r * 8192 + (ks & 1) * 64 + kbyte;
    short8 a0 = *(const short8*)(aw0 + ks * 512);
    short8 a1 = *(const short8*)(aw0 + (18 + ks) * 512);
    const int d = m16 + c - 1;  // -1..16
    const int base = (koff + d * 128) ^ ((d & 7) << 4);
    const bool edgeLo = (c == 0) && (m16 == 0);
    const bool edgeHi = (c == 2) && (m16 == 15);
#pragma unroll
    for (int n = 0; n < 8; ++n) {
      const int orw = n >> 2, n4 = n & 3;
      short8 bv = *(const short8*)(SB + base + orw * 8192 + n4 * 2048);
      if (c == 0 && n4 == 0) { if (edgeLo) bv = z8; }
      if (c == 2 && n4 == 3) { if (edgeHi) bv = z8; }
      acc[0][n] = __builtin_amdgcn_mfma_f32_16x16x32_bf16(a0, bv, acc[0][n], 0, 0, 0);
      acc[1][n] = __builtin_amdgcn_mfma_f32_16x16x32_bf16(a1, bv, acc[1][n], 0, 0, 0);
    }
  }

  // epilogue: relu(acc + b2) + pe -> bf16, two rows
  const float inv63 = 1.f / 63.f;
#pragma unroll
  for (int ct = 0; ct < 2; ++ct) {
    const int cot = wv * 2 + ct;
#pragma unroll
    for (int r = 0; r < 4; ++r) {
      const int co = cot * 16 + g * 4 + r;
      const float bias = b2[co];
      const float W0 = dw[co * 4 + 0], W1 = dw[co * 4 + 1];
      const float W2 = dw[co * 4 + 2], W3 = dw[co * 4 + 3];
      const float c23 = W2 + W3 + db[co];
      const float s02 = W0 - W2, s13 = W1 - W3;
#pragma unroll
      for (int orw = 0; orw < 2; ++orw) {
        const int h = 2 * hp + orw;
        const float pe0 = (float)h * inv63 * s02 + c23;
        u16* orow = x2b + (((size_t)(b * 128 + co)) << 12) + h * 64;
#pragma unroll
        for (int n4 = 0; n4 < 4; ++n4) {
          const int w = n4 * 16 + m16;
          orow[w] = f2bf(fmaxf(acc[ct][orw * 4 + n4][r] + bias, 0.f) + pe0 +
                         (float)w * inv63 * s13);
        }
      }
    }
  }
}

// ---------------- k3: masked spatial max in packed mapped-u16 domain ---------
__global__ __launch_bounds__(256) void k3_roi(const u16* __restrict__ x2b,
                                              const unsigned* __restrict__ rmask,
                                              u32* __restrict__ partial) {
  __shared__ alignas(16) char LB[18688];
  u32* XSU = (u32*)LB;           // [16 c][260] (256 used)
  u32* MS = (u32*)(LB + 16640);  // 512 mask words
  const int cg = blockIdx.x, pq = blockIdx.y, b = blockIdx.z;
  const int t = threadIdx.x, wv = t >> 6, lane = t & 63;
  const int p0 = pq * 512;

#pragma unroll
  for (int i = 0; i < 4; ++i) {  // stage+map 16 c x 512 pos
    const int f4 = i * 256 + t;
    const int c = f4 >> 6, cidx = f4 & 63;
    uint4 v = *(const uint4*)&x2b[(((size_t)(b * 128 + cg * 16 + c)) << 12) + p0 + cidx * 8];
    v.x = map2(v.x); v.y = map2(v.y); v.z = map2(v.z); v.w = map2(v.w);
    *(uint4*)&XSU[c * 260 + cidx * 4] = v;
  }
  if (t < 128) *(uint4*)&MS[t * 4] = *(const uint4*)&rmask[b * 4096 + p0 + t * 4];
  __syncthreads();

  const int og = lane >> 3, cu = lane & 7;
  const u32* r0 = XSU + (2 * cu) * 260;
  const u32* r1 = XSU + (2 * cu + 1) * 260;
  const int ps = wv * 128;

  u32 a[4][2];  // packed running max; 0 = mapped -inf
#pragma unroll
  for (int r = 0; r < 4; ++r) { a[r][0] = 0u; a[r][1] = 0u; }

  for (int pi = 0; pi < 32; ++pi) {
    const int p = ps + pi * 4;
    const uint4 mw = *(const uint4*)&MS[p];  // uniform -> broadcast
    const uint2 xa = *(const uint2*)&r0[p >> 1];
    const uint2 xb = *(const uint2*)&r1[p >> 1];
#pragma unroll
    for (int r = 0; r < 4; ++r) {
      const int o = og * 4 + r;
      u32 t0 = (u32)((int)(mw.x << (31 - o)) >> 31);
      u32 t1 = (u32)((int)(mw.y << (31 - o)) >> 31);
      u32 pm = (t0 & 0xFFFFu) | (t1 & 0xFFFF0000u);
      a[r][0] = pkmaxu(a[r][0], (xa.x & pm) | (0x80008000u & ~pm));
      a[r][1] = pkmaxu(a[r][1], (xb.x & pm) | (0x80008000u & ~pm));
      t0 = (u32)((int)(mw.z << (31 - o)) >> 31);
      t1 = (u32)((int)(mw.w << (31 - o)) >> 31);
      pm = (t0 & 0xFFFFu) | (t1 & 0xFFFF0000u);
      a[r][0] = pkmaxu(a[r][0], (xa.y & pm) | (0x80008000u & ~pm));
      a[r][1] = pkmaxu(a[r][1], (xb.y & pm) | (0x80008000u & ~pm));
    }
  }

  __syncthreads();      // XSU/MS dead; reuse LB for reduction
  u32* RED = (u32*)LB;  // [4 wv][64 lane][8 slot]
#pragma unroll
  for (int r = 0; r < 4; ++r) {  // static indices only (rule #20)
    RED[(wv * 64 + lane) * 8 + r * 2 + 0] = a[r][0];
    RED[(wv * 64 + lane) * 8 + r * 2 + 1] = a[r][1];
  }
  __syncthreads();
  {
    const int o = t >> 3, clp = t & 7;
    const int sl = (o >> 2) * 8 + clp;
    const int s0 = (o & 3) * 2;
    u32 m0 = 0u, m1 = 0u;
#pragma unroll
    for (int w = 0; w < 4; ++w) {
      const uint2 q = *(const uint2*)&RED[(w * 64 + sl) * 8 + s0];
      m0 = pkmaxu(m0, q.x);
      m1 = pkmaxu(m1, q.y);
    }
    u32 f0l = m0 & 0xFFFFu, f0h = m0 >> 16;
    u32 f1l = m1 & 0xFFFFu, f1h = m1 >> 16;
    const u32 f0 = f0l > f0h ? f0l : f0h;
    const u32 f1 = f1l > f1h ? f1l : f1h;
    partial[(size_t)pq * 32768 + ((size_t)b * 32 + o) * 64 + cg * 8 + clp] =
        f0 | (f1 << 16);
  }
}

// ---------------- k4: merge 8 pq-partials (packed), unmap -> f32 out ---------
__global__ __launch_bounds__(256) void k4_merge(const u32* __restrict__ partial,
                                                float* __restrict__ out) {
  const int idx = blockIdx.x * 256 + threadIdx.x;  // 0..32767 u32s
  u32 v = partial[idx];
#pragma unroll
  for (int q = 1; q < 8; ++q) v = pkmaxu(v, partial[q * 32768 + idx]);
  float2 o2;
  o2.x = unmap1(v & 0xFFFFu);
  o2.y = unmap1(v >> 16);
  *(float2*)&out[idx * 2] = o2;
}

}  // namespace

extern "C" void kernel_launch(void* const* d_in, const int* in_sizes, int n_in,
                              void* d_out, int out_size, void* d_ws, size_t ws_size,
                              hipStream_t stream) {
  const float* images = (const float*)d_in[0];
  const unsigned* rois = (const unsigned*)d_in[1];
  const float* w1 = (const float*)d_in[2];
  const float* b1 = (const float*)d_in[3];
  const float* w2 = (const float*)d_in[4];
  const float* b2 = (const float*)d_in[5];
  const float* dw = (const float*)d_in[6];
  const float* db = (const float*)d_in[7];
  float* out = (float*)d_out;

  char* ws = (char*)d_ws;
  // rmask 256KB @0 ; pooledT 8MB @0x40000 (dead after k2; partial 1MB reuses);
  // Aw2 144KB @0x840000 ; Aw1 20KB @0x864000 ; imgT 8MB @0x900000 (dead after
  // k1) ; x2b bf16 16MB @0x900000 (overlaps imgT, written by k2).
  unsigned* rmask = (unsigned*)(ws);
  u16* pooledT = (u16*)(ws + 0x40000);
  u16* Aw2 = (u16*)(ws + 0x840000);
  u16* Aw1 = (u16*)(ws + 0x864000);
  u16* imgT = (u16*)(ws + 0x900000);
  u16* x2b = (u16*)(ws + 0x900000);
  u32* partial = (u32*)(ws + 0x40000);

  hipLaunchKernelGGL(kiop, dim3(2504), dim3(256), 0, stream,
                     images, imgT, rois, rmask, w2, Aw2, w1, Aw1);
  hipLaunchKernelGGL(k1_mfma, dim3(64, 16), dim3(256), 0, stream, imgT, Aw1, b1, pooledT);
  hipLaunchKernelGGL(k2_mfma, dim3(32, 16), dim3(256), 0, stream, pooledT, Aw2, b2, dw, db, x2b);
  hipLaunchKernelGGL(k3_roi, dim3(8, 8, 16), dim3(256), 0, stream, x2b, rmask, partial);
  hipLaunchKernelGGL(k4_merge, dim3(128), dim3(256), 0, stream, partial, out);
}

// Round 11
// 64.286 us; speedup vs baseline: 5.4874x; 1.1142x over previous
//
#include <hip/hip_runtime.h>

// B=16, 12 in-ch, 128x128 imgs; conv1->64ch +pool -> 64x64; conv2->128ch (+PE);
// roi max -> out (16,32,128) f32.
//
// R11 = R10 with k3 fused into k2's epilogue (x2b eliminated; single-stream
// kernel-boundary drains were ~half the runtime). Pipeline: kiop (imgT+rmask+
// weight frags) ; k1_mfma (conv1+relu+pool -> bf16 pooledT) ; k2f (conv2+relu
// +PE -> in-LDS mapped-u16 tile -> in-block roi-max scan -> partial[hp]) ;
// k4_merge (32-slab packed max, unmap -> f32 out).

typedef __attribute__((ext_vector_type(8))) short short8;   // MFMA bf16 A/B frag
typedef __attribute__((ext_vector_type(4))) float f32x4;    // MFMA C/D frag
typedef __attribute__((ext_vector_type(4))) unsigned short us4;
typedef __attribute__((ext_vector_type(2))) unsigned short u16x2;
typedef unsigned short u16;
typedef unsigned int u32;

__device__ __forceinline__ u16 f2bf(float f) {  // RNE f32 -> bf16 bits
  u32 u = __builtin_bit_cast(u32, f);
  return (u16)((u + 0x7fffu + ((u >> 16) & 1u)) >> 16);
}
__device__ __forceinline__ u32 pkmaxu(u32 a, u32 b) {  // v_pk_max_u16
  u16x2 x = __builtin_bit_cast(u16x2, a), y = __builtin_bit_cast(u16x2, b);
  return __builtin_bit_cast(u32, __builtin_elementwise_max(x, y));
}
__device__ __forceinline__ u32 map2(u32 v) {  // monotone bf16->u16 map, x2
  u32 flip = ((v & 0x80008000u) >> 15) * 0xFFFFu;
  return v ^ (flip | 0x80008000u);
}
__device__ __forceinline__ float unmap1(u32 m) {  // mapped u16 -> f32
  u32 b = m ^ ((m & 0x8000u) ? 0x8000u : 0xFFFFu);
  return __builtin_bit_cast(float, b << 16);
}

namespace {

// ---------------- kiop: imgT | rmask | Aw2 | Aw1 (fused prep) ----------------
__global__ __launch_bounds__(256) void kiop(const float* __restrict__ img,
                                            u16* __restrict__ imgT,
                                            const unsigned* __restrict__ rois,
                                            unsigned* __restrict__ rmask,
                                            const float* __restrict__ w2,
                                            u16* __restrict__ Aw2,
                                            const float* __restrict__ w1,
                                            u16* __restrict__ Aw1) {
  __shared__ alignas(16) u16 ST[2048];
  const int bx = blockIdx.x;
  const int t = threadIdx.x;
  if (bx < 2048) {  // images f32 -> bf16 imgT [b][row][col][ci16], pad ci->0
    const int row = bx & 127, b = bx >> 7;
#pragma unroll
    for (int i = 0; i < 2; ++i) {
      const int e = i * 256 + t;
      ST[(e >> 2) * 16 + 12 + (e & 3)] = 0;
    }
#pragma unroll
    for (int i = 0; i < 6; ++i) {
      const int e = i * 256 + t;
      const int ci = e >> 7, col = e & 127;
      const float v = img[(((size_t)(b * 12 + ci)) << 14) + row * 128 + col];
      ST[col * 16 + ci] = f2bf(v);
    }
    __syncthreads();
    us4* dst = (us4*)(imgT + (((size_t)(b * 128 + row)) << 11));
#pragma unroll
    for (int i = 0; i < 2; ++i) {
      const int q = i * 256 + t;
      dst[q] = *(const us4*)&ST[q * 4];
    }
  } else if (bx < 2176) {  // rois[:,:,::2,::2] -> 32-bit object mask
    const int lane = t & 63;
    u32 ok = 1u;
#pragma unroll
    for (int i = 0; i < 4; ++i) {
      u32 v = rois[lane * 4 + i];
      ok &= ((v <= 1u) || (v == 0x3f800000u)) ? 1u : 0u;
    }
    const bool isWord = (__all((int)ok) != 0);
    const unsigned char* roisB = (const unsigned char*)rois;
    const int pi = (bx - 2048) * 256 + t;  // 0..32767
    const int b = pi >> 11;
    const int pp = pi & 2047;
    const int h = pp >> 5;
    const int wp = pp & 31;
    const size_t base = (size_t)b * 32 * 16384 + (size_t)(2 * h) * 128 + 4 * wp;
    u32 m0 = 0, m1 = 0;
#pragma unroll
    for (int o = 0; o < 32; ++o) {
      const size_t idx = base + (size_t)o * 16384;
      if (isWord) {
        const uint4 q = *(const uint4*)&rois[idx];
        m0 |= (u32)(q.x != 0u) << o;
        m1 |= (u32)(q.z != 0u) << o;
      } else {
        const u32 q = *(const u32*)&roisB[idx];
        m0 |= (u32)((q & 0xffu) != 0u) << o;
        m1 |= (u32)((q & 0xff0000u) != 0u) << o;
      }
    }
    *(uint2*)&rmask[b * 4096 + h * 64 + wp * 2] = make_uint2(m0, m1);
  } else if (bx < 2464) {  // w2 -> Aw2 frags
    const int idx = (bx - 2176) * 256 + t;  // 0..73727
    const int j = idx & 7;
    const int lane = (idx >> 3) & 63;
    const int t3 = idx >> 9;
    const int ks = t3 % 18, cot = t3 / 18;
    const int m = lane & 15, g = lane >> 4;
    const int co = cot * 16 + m;
    const int k = ks * 32 + g * 8 + j;
    const int rc = k >> 6, ci = k & 63;
    Aw2[idx] = f2bf(w2[co * 576 + ci * 9 + rc]);
  } else {  // w1 -> Aw1 frags, K padded 108->160
    const int idx = (bx - 2464) * 256 + t;  // 0..10239
    const int j = idx & 7;
    const int lane = (idx >> 3) & 63;
    const int t3 = idx >> 9;
    const int ks = t3 % 5, cot = t3 / 5;
    const int m = lane & 15, g = lane >> 4;
    const int co = cot * 16 + m;
    const int k = ks * 32 + g * 8 + j;
    const int rc = k >> 4, cip = k & 15;
    const float v = (rc < 9 && cip < 12) ? w1[co * 108 + cip * 9 + rc] : 0.f;
    Aw1[idx] = f2bf(v);
  }
}

// ---------------- k1: conv1 (MFMA) + bias + relu + pool -> pooledT bf16 ------
__global__ __launch_bounds__(256) void k1_mfma(const u16* __restrict__ imgT,
                                               const u16* __restrict__ Aw1,
                                               const float* __restrict__ b1,
                                               u16* __restrict__ pooledT) {
  __shared__ alignas(16) u16 SIMG[8192];   // 16 KB, swizzled
  __shared__ alignas(16) u16 PT[64 * 68];  // pooled [pw][co]
  const int h2 = blockIdx.x, b = blockIdx.y;
  const int t = threadIdx.x, wv = t >> 6, l = t & 63;

#pragma unroll
  for (int i = 0; i < 4; ++i) {  // stage 4 rows x 4KB (swizzled store)
    const int q = i * 256 + t;
    const int sr = q >> 8, off = q & 255;
    const int irow = 2 * h2 - 1 + sr;
    short8 v = {0, 0, 0, 0, 0, 0, 0, 0};
    if ((unsigned)irow < 128u)
      v = *(const short8*)(imgT + (((size_t)(b * 128 + irow)) << 11) + off * 8);
    *(short8*)((char*)SIMG + ((q * 16) ^ (((q >> 3) & 1) << 4))) = v;
  }
  __syncthreads();

  const int m16 = l & 15, g = l >> 4;
  const int colhalf = wv >> 1, cotbase = (wv & 1) * 2;
  const int cipb = (g & 1) * 16;
  f32x4 acc[2][8];
#pragma unroll
  for (int ct = 0; ct < 2; ++ct)
#pragma unroll
    for (int pt = 0; pt < 8; ++pt) acc[ct][pt] = (f32x4){0.f, 0.f, 0.f, 0.f};

  const u16* awb = Aw1 + (size_t)l * 8;
  const short8 z8 = {0, 0, 0, 0, 0, 0, 0, 0};

#pragma unroll
  for (int ks = 0; ks < 5; ++ks) {
    short8 a0 = *(const short8*)(awb + (cotbase * 5 + ks) * 512);
    short8 a1 = *(const short8*)(awb + ((cotbase + 1) * 5 + ks) * 512);
    const bool pz = (ks == 4) && (g >= 2);  // zero-padded K slots
    const int rc = pz ? 0 : (2 * ks + (g >> 1));
    const int rr = (rc * 11) >> 5;  // rc/3
    const int cc = rc - rr * 3;     // rc%3
    const int d = m16 - 1 + cc;     // -1..16
    const int sb = (d < 0) ? 1 : ((d >> 2) & 1);
    const int base = rr * 4096 + d * 32 + colhalf * 2048 + (cipb ^ (sb << 4));
    const bool killLo = (cc == 0) && (m16 == 0) && (colhalf == 0);
    const bool killHi = (cc == 2) && (m16 == 15) && (colhalf == 1);
#pragma unroll
    for (int pt = 0; pt < 8; ++pt) {
      const int r01 = pt >> 2, ct2 = pt & 3;
      short8 bv = *(const short8*)((const char*)SIMG + base + r01 * 4096 + ct2 * 512);
      bool kill = pz;
      if (ct2 == 0) kill = kill || killLo;
      if (ct2 == 3) kill = kill || killHi;
      if (kill) bv = z8;
      acc[0][pt] = __builtin_amdgcn_mfma_f32_16x16x32_bf16(a0, bv, acc[0][pt], 0, 0, 0);
      acc[1][pt] = __builtin_amdgcn_mfma_f32_16x16x32_bf16(a1, bv, acc[1][pt], 0, 0, 0);
    }
  }

  // relu + 2x2 pool -> PT[pw][co]
#pragma unroll
  for (int ct = 0; ct < 2; ++ct) {
    const int cot = cotbase + ct;
#pragma unroll
    for (int r = 0; r < 4; ++r) {
      const int co = cot * 16 + g * 4 + r;
      const float bias = b1[co];
#pragma unroll
      for (int ct2 = 0; ct2 < 4; ++ct2) {
        float v0 = fmaxf(acc[ct][ct2][r] + bias, 0.f);
        float v1 = fmaxf(acc[ct][4 + ct2][r] + bias, 0.f);
        float vv = fmaxf(v0, v1);
        vv = fmaxf(vv, __shfl_xor(vv, 1, 64));
        if (!(m16 & 1)) {
          const int pw = colhalf * 32 + ct2 * 8 + (m16 >> 1);
          PT[pw * 68 + co] = f2bf(vv);
        }
      }
    }
  }
  __syncthreads();
  u16* dst = pooledT + (((size_t)(b * 64 + h2)) << 12);
#pragma unroll
  for (int i = 0; i < 4; ++i) {
    const int e = (i * 256 + t) * 4;
    const int pw = e >> 6, co = e & 63;
    *(us4*)(dst + e) = *(const us4*)&PT[pw * 68 + co];
  }
}

// ---------------- k2f: conv2 (MFMA) + bias + relu + PE + in-block roi-max ----
// 2 output rows per block (grid 32x16). MFMA loop = R10 verbatim. Epilogue:
// write mapped-u16 x2 tile [pos 0..127][co 0..127] into reused SB (swizzle
// ^((pos&7)<<4): stores/reads <=2-way conflicts), then scan: thread =
// (o-group-of-4, co-quad) owns 16 cells with 8 packed u32 accums, iterates
// all 128 staged pos (mask word wave-uniform broadcast). No cross-wave
// reduction needed. partial[hp][b][o][co/2] packed u32.
__global__ __launch_bounds__(256) void k2f(const u16* __restrict__ pooledT,
                                           const u16* __restrict__ Aw,
                                           const float* __restrict__ b2,
                                           const float* __restrict__ dw,
                                           const float* __restrict__ db,
                                           const unsigned* __restrict__ rmask,
                                           u32* __restrict__ partial) {
  __shared__ alignas(16) char SB[32768];  // stage 4 rows | then mapped out-tile
  __shared__ u32 MS[128];                 // 2 rows of mask words
  const int hp = blockIdx.x, b = blockIdx.y;
  const int t = threadIdx.x, wv = t >> 6, l = t & 63;

#pragma unroll
  for (int i = 0; i < 8; ++i) {  // stage rows 2hp-1..2hp+2, T2 XOR swizzle
    const int chunk = i * 4 + wv;
    const int row = chunk >> 3;
    const int hin = 2 * hp - 1 + row;
    short8 v = {0, 0, 0, 0, 0, 0, 0, 0};
    if ((unsigned)hin < 64u)
      v = *(const short8*)(pooledT + (((size_t)(b * 64 + hin)) << 12) +
                           ((chunk & 7) << 9) + l * 8);
    const int lin = chunk * 1024 + l * 16;
    *(short8*)(SB + (lin ^ (((lin >> 7) & 7) << 4))) = v;
  }
  if (t < 128) MS[t] = rmask[b * 4096 + hp * 128 + t];
  __syncthreads();

  const int m16 = l & 15, g = l >> 4;
  const int kbyte = g * 16;
  f32x4 acc[2][8];  // [ct][n], n = orw*4 + n4
#pragma unroll
  for (int ct = 0; ct < 2; ++ct)
#pragma unroll
    for (int n = 0; n < 8; ++n) acc[ct][n] = (f32x4){0.f, 0.f, 0.f, 0.f};

  const u16* aw0 = Aw + (size_t)wv * 36 * 512 + l * 8;  // cot = 2wv
  const short8 z8 = {0, 0, 0, 0, 0, 0, 0, 0};

#pragma unroll
  for (int ks = 0; ks < 18; ++ks) {
    const int rc = ks >> 1, r = rc / 3, c = rc % 3;  // compile-time
    const int koff = r * 8192 + (ks & 1) * 64 + kbyte;
    short8 a0 = *(const short8*)(aw0 + ks * 512);
    short8 a1 = *(const short8*)(aw0 + (18 + ks) * 512);
    const int d = m16 + c - 1;  // -1..16
    const int base = (koff + d * 128) ^ ((d & 7) << 4);
    const bool edgeLo = (c == 0) && (m16 == 0);
    const bool edgeHi = (c == 2) && (m16 == 15);
#pragma unroll
    for (int n = 0; n < 8; ++n) {
      const int orw = n >> 2, n4 = n & 3;
      short8 bv = *(const short8*)(SB + base + orw * 8192 + n4 * 2048);
      if (c == 0 && n4 == 0) { if (edgeLo) bv = z8; }
      if (c == 2 && n4 == 3) { if (edgeHi) bv = z8; }
      acc[0][n] = __builtin_amdgcn_mfma_f32_16x16x32_bf16(a0, bv, acc[0][n], 0, 0, 0);
      acc[1][n] = __builtin_amdgcn_mfma_f32_16x16x32_bf16(a1, bv, acc[1][n], 0, 0, 0);
    }
  }

  __syncthreads();  // all waves done reading SB (WAR before tile overwrite)

  // epilogue: relu(acc+b2)+pe -> bf16 -> map -> SB[pos][co] (u32 pair stores)
  const float inv63 = 1.f / 63.f;
#pragma unroll
  for (int ct = 0; ct < 2; ++ct) {
    const int cot = wv * 2 + ct;
#pragma unroll
    for (int r2 = 0; r2 < 2; ++r2) {  // co pair (r = 2*r2 + j)
      const int co0 = cot * 16 + g * 4 + r2 * 2;
      const float bias0 = b2[co0], bias1 = b2[co0 + 1];
      const float pA0 = dw[co0 * 4 + 0] - dw[co0 * 4 + 2];          // s02
      const float pB0 = dw[co0 * 4 + 1] - dw[co0 * 4 + 3];          // s13
      const float pC0 = dw[co0 * 4 + 2] + dw[co0 * 4 + 3] + db[co0];
      const float pA1 = dw[co0 * 4 + 4] - dw[co0 * 4 + 6];
      const float pB1 = dw[co0 * 4 + 5] - dw[co0 * 4 + 7];
      const float pC1 = dw[co0 * 4 + 6] + dw[co0 * 4 + 7] + db[co0 + 1];
#pragma unroll
      for (int orw = 0; orw < 2; ++orw) {
        const float gy = (float)(2 * hp + orw) * inv63;
        const float pe00 = gy * pA0 + pC0;
        const float pe01 = gy * pA1 + pC1;
#pragma unroll
        for (int n4 = 0; n4 < 4; ++n4) {
          const int w = n4 * 16 + m16;
          const int pos = orw * 64 + w;
          const float gx = (float)w * inv63;
          const float v0 = fmaxf(acc[ct][orw * 4 + n4][r2 * 2 + 0] + bias0, 0.f)
                           + pe00 + gx * pB0;
          const float v1 = fmaxf(acc[ct][orw * 4 + n4][r2 * 2 + 1] + bias1, 0.f)
                           + pe01 + gx * pB1;
          const u32 pk = map2((u32)f2bf(v0) | ((u32)f2bf(v1) << 16));
          *(u32*)(SB + ((pos * 256 + co0 * 2) ^ ((pos & 7) << 4))) = pk;
        }
      }
    }
  }
  __syncthreads();

  // in-block roi-max scan: thread = (og 0..7, coq 0..31) -> 4 o x 4 co cells
  const int og = t >> 5, coq = t & 31;
  u32 a0[4], a1[4];  // [r]; a0 = co {4coq,4coq+1}, a1 = co {4coq+2,4coq+3}
#pragma unroll
  for (int r = 0; r < 4; ++r) { a0[r] = 0u; a1[r] = 0u; }
  for (int pos = 0; pos < 128; ++pos) {
    const u32 mw = MS[pos];  // wave-uniform -> broadcast
    const uint2 x = *(const uint2*)(SB + ((pos * 256 + coq * 8) ^ ((pos & 7) << 4)));
#pragma unroll
    for (int r = 0; r < 4; ++r) {
      const int o = og * 4 + r;
      const u32 am = (u32)((int)(mw << (31 - o)) >> 31);  // v_bfe_i32
      a0[r] = pkmaxu(a0[r], (x.x & am) | (0x80008000u & ~am));  // v_bfi
      a1[r] = pkmaxu(a1[r], (x.y & am) | (0x80008000u & ~am));
    }
  }
  u32* pslab = partial + (size_t)hp * 32768;
#pragma unroll
  for (int r = 0; r < 4; ++r) {  // static indices only (rule #20)
    const int o = og * 4 + r;
    *(uint2*)&pslab[((b * 32 + o) << 6) + coq * 2] = make_uint2(a0[r], a1[r]);
  }
}

// ---------------- k4: merge 32 hp-partials (packed), unmap -> f32 out --------
__global__ __launch_bounds__(256) void k4_merge(const u32* __restrict__ partial,
                                                float* __restrict__ out) {
  const int idx = blockIdx.x * 256 + threadIdx.x;  // 0..32767 u32 cells
  u32 v = partial[idx];
#pragma unroll
  for (int q = 1; q < 32; ++q) v = pkmaxu(v, partial[q * 32768 + idx]);
  float2 o2;
  o2.x = unmap1(v & 0xFFFFu);
  o2.y = unmap1(v >> 16);
  *(float2*)&out[idx * 2] = o2;
}

}  // namespace

extern "C" void kernel_launch(void* const* d_in, const int* in_sizes, int n_in,
                              void* d_out, int out_size, void* d_ws, size_t ws_size,
                              hipStream_t stream) {
  const float* images = (const float*)d_in[0];
  const unsigned* rois = (const unsigned*)d_in[1];
  const float* w1 = (const float*)d_in[2];
  const float* b1 = (const float*)d_in[3];
  const float* w2 = (const float*)d_in[4];
  const float* b2 = (const float*)d_in[5];
  const float* dw = (const float*)d_in[6];
  const float* db = (const float*)d_in[7];
  float* out = (float*)d_out;

  char* ws = (char*)d_ws;
  // rmask 256KB @0 ; pooledT 8MB @0x40000 ; Aw2 144KB @0x840000 ; Aw1 20KB
  // @0x864000 ; imgT 8MB @0x900000 (dead after k1) ; partial 4MB @0x900000
  // (overlaps dead imgT; written by k2f, read by k4).
  unsigned* rmask = (unsigned*)(ws);
  u16* pooledT = (u16*)(ws + 0x40000);
  u16* Aw2 = (u16*)(ws + 0x840000);
  u16* Aw1 = (u16*)(ws + 0x864000);
  u16* imgT = (u16*)(ws + 0x900000);
  u32* partial = (u32*)(ws + 0x900000);

  hipLaunchKernelGGL(kiop, dim3(2504), dim3(256), 0, stream,
                     images, imgT, rois, rmask, w2, Aw2, w1, Aw1);
  hipLaunchKernelGGL(k1_mfma, dim3(64, 16), dim3(256), 0, stream, imgT, Aw1, b1, pooledT);
  hipLaunchKernelGGL(k2f, dim3(32, 16), dim3(256), 0, stream,
                     pooledT, Aw2, b2, dw, db, rmask, partial);
  hipLaunchKernelGGL(k4_merge, dim3(128), dim3(256), 0, stream, partial, out);
}